// Round 15
// baseline (1200.135 us; speedup 1.0000x reference)
//
#include <hip/hip_runtime.h>
#include <cmath>

// ---------------------------------------------------------------------------
// GCN 3-layer forward on MI355X — round 13.
// vs round 12 (672us, k_agg128 2x96us top, FETCH 218MB vs 102MB floor):
// (1) src-windowed 4-pass gather in k_agg128: pass p touches only a 4MB hb
//     window (fits per-XCD L2) -> each XCD fetches each line ~once.
//     Filter is wave-uniform (src same across lanes) -> branch, cheap.
// (2) dinv premultiplied into hb at GEMM output (hb = h*dinv, bf16):
//     removes per-edge dinv[s] dependent load from the gather chain.
//     out[d] = (sum_s hb[s] + hb[d]) * dinv[d] + b   (identical math).
// ---------------------------------------------------------------------------

typedef unsigned short ushort_t;

__device__ __forceinline__ ushort_t f2bf(float x) {
    unsigned int u = __float_as_uint(x);
    u += 0x7FFF + ((u >> 16) & 1);   // round-to-nearest-even
    return (ushort_t)(u >> 16);
}
__device__ __forceinline__ float bf2f(ushort_t b) {
    return __uint_as_float(((unsigned int)b) << 16);
}

__global__ void k_hist(const int* __restrict__ dst, int* __restrict__ hist, int e) {
    int i = blockIdx.x * blockDim.x + threadIdx.x;
    int stride = gridDim.x * blockDim.x;
    for (; i < e; i += stride) atomicAdd(&hist[dst[i]], 1);
}

// wave-aggregated row allocation: in-wave exclusive prefix of hist via shfl,
// one atomicAdd per wave on gcounter. Row placement order is arbitrary.
__global__ void k_alloc(const int* __restrict__ hist, int* __restrict__ gcounter,
                        int* __restrict__ row_start, int* __restrict__ cursor,
                        float* __restrict__ dinv, int n) {
    const int i = blockIdx.x * blockDim.x + threadIdx.x;
    const int lane = threadIdx.x & 63;
    int h = (i < n) ? hist[i] : 0;
    int pre = h;                              // inclusive prefix within wave
    #pragma unroll
    for (int off = 1; off < 64; off <<= 1) {
        int t = __shfl_up(pre, off, 64);
        if (lane >= off) pre += t;
    }
    int wavesum = __shfl(pre, 63, 64);
    int base = 0;
    if (lane == 63) base = atomicAdd(gcounter, wavesum);
    base = __shfl(base, 63, 64);
    if (i < n) {
        int rs = base + (pre - h);            // exclusive prefix
        row_start[i] = rs;
        cursor[i] = rs;
        dinv[i] = rsqrtf(1.0f + (float)h);
    }
}

// multi-pass scatter: pass p handles dst in [p*8192,(p+1)*8192) so concurrent
// ssrc writes are confined to a ~512KB window (L2 lines fill before eviction).
__global__ void k_scatter(const int* __restrict__ src, const int* __restrict__ dst,
                          int* __restrict__ cursor, ushort_t* __restrict__ ssrc, int e) {
    const int tid0 = blockIdx.x * blockDim.x + threadIdx.x;
    const int stride = gridDim.x * blockDim.x;
    for (int p = 0; p < 7; ++p) {          // 50000>>13 == 6, so passes 0..6
        for (int i = tid0; i < e; i += stride) {
            int d = dst[i];
            if ((d >> 13) == p) {
                int pos = atomicAdd(&cursor[d], 1);
                ssrc[pos] = (ushort_t)src[i];
            }
        }
    }
}

// GEMM: hb_bf16[gr] = (in[gr] @ W) * dinv[gr]  (dinv premultiplied for agg)
template<int FOUT>
__global__ __launch_bounds__(256) void k_gemm(const float* __restrict__ in,
                                              const float* __restrict__ W,
                                              const float* __restrict__ dinv,
                                              ushort_t* __restrict__ out, int n) {
    __shared__ float Ws[128 * FOUT];
    __shared__ float Xs[32][129];
    const int tid = threadIdx.x;
    const int row0 = blockIdx.x * 32;

    for (int i = tid; i < 128 * FOUT / 4; i += 256)
        ((float4*)Ws)[i] = ((const float4*)W)[i];

    for (int i = tid; i < 1024; i += 256) {
        int r = i >> 5;
        int c = (i & 31) << 2;
        int gr = row0 + r;
        float4 v = make_float4(0.f, 0.f, 0.f, 0.f);
        if (gr < n) v = *(const float4*)(in + (size_t)gr * 128 + c);
        Xs[r][c + 0] = v.x; Xs[r][c + 1] = v.y;
        Xs[r][c + 2] = v.z; Xs[r][c + 3] = v.w;
    }
    __syncthreads();

    if constexpr (FOUT == 128) {
        const int tc = (tid & 15) * 8;
        const int tr = (tid >> 4) * 2;
        float acc0[8] = {0,0,0,0,0,0,0,0};
        float acc1[8] = {0,0,0,0,0,0,0,0};
        for (int k = 0; k < 128; ++k) {
            float a0 = Xs[tr][k];
            float a1 = Xs[tr + 1][k];
            float4 b0 = *(const float4*)&Ws[k * 128 + tc];
            float4 b1 = *(const float4*)&Ws[k * 128 + tc + 4];
            acc0[0] += a0 * b0.x; acc0[1] += a0 * b0.y;
            acc0[2] += a0 * b0.z; acc0[3] += a0 * b0.w;
            acc0[4] += a0 * b1.x; acc0[5] += a0 * b1.y;
            acc0[6] += a0 * b1.z; acc0[7] += a0 * b1.w;
            acc1[0] += a1 * b0.x; acc1[1] += a1 * b0.y;
            acc1[2] += a1 * b0.z; acc1[3] += a1 * b0.w;
            acc1[4] += a1 * b1.x; acc1[5] += a1 * b1.y;
            acc1[6] += a1 * b1.z; acc1[7] += a1 * b1.w;
        }
        int gr = row0 + tr;
        if (gr < n) {
            float dv = dinv[gr];
            uint4 o;
            o.x = (unsigned)f2bf(acc0[0]*dv) | ((unsigned)f2bf(acc0[1]*dv) << 16);
            o.y = (unsigned)f2bf(acc0[2]*dv) | ((unsigned)f2bf(acc0[3]*dv) << 16);
            o.z = (unsigned)f2bf(acc0[4]*dv) | ((unsigned)f2bf(acc0[5]*dv) << 16);
            o.w = (unsigned)f2bf(acc0[6]*dv) | ((unsigned)f2bf(acc0[7]*dv) << 16);
            *(uint4*)(out + (size_t)gr * 128 + tc) = o;
        }
        if (gr + 1 < n) {
            float dv = dinv[gr + 1];
            uint4 o;
            o.x = (unsigned)f2bf(acc1[0]*dv) | ((unsigned)f2bf(acc1[1]*dv) << 16);
            o.y = (unsigned)f2bf(acc1[2]*dv) | ((unsigned)f2bf(acc1[3]*dv) << 16);
            o.z = (unsigned)f2bf(acc1[4]*dv) | ((unsigned)f2bf(acc1[5]*dv) << 16);
            o.w = (unsigned)f2bf(acc1[6]*dv) | ((unsigned)f2bf(acc1[7]*dv) << 16);
            *(uint4*)(out + (size_t)(gr + 1) * 128 + tc) = o;
        }
    } else {
        const int tc = (tid & 7) * 5;
        const int tr = tid >> 3;
        float acc[5] = {0,0,0,0,0};
        for (int k = 0; k < 128; ++k) {
            float a = Xs[tr][k];
            #pragma unroll
            for (int j = 0; j < 5; ++j) acc[j] += a * Ws[k * 40 + tc + j];
        }
        int gr = row0 + tr;
        if (gr < n) {
            float dv = dinv[gr];
            #pragma unroll
            for (int j = 0; j < 5; ++j) out[(size_t)gr * 40 + tc + j] = f2bf(acc[j] * dv);
        }
    }
}

// CSR aggregation, 128 bf16 premultiplied features. One wave per dst node.
// 4 src-window passes: pass p gathers only rows with src>>14==p (4MB window
// fits per-XCD L2). Filter is wave-uniform -> cheap branch.
template<bool RELU>
__global__ __launch_bounds__(256) void k_agg128(const int* __restrict__ row_start,
                                                const int* __restrict__ row_end,
                                                const ushort_t* __restrict__ hb,
                                                const float* __restrict__ dinv,
                                                const float* __restrict__ bias,
                                                const ushort_t* __restrict__ ssrc,
                                                float* __restrict__ ag, int n) {
    const int wid = (blockIdx.x * 256 + threadIdx.x) >> 6;
    const int lane = threadIdx.x & 63;
    if (wid >= n) return;
    const int d = wid;
    const int beg = row_start[d];
    const int end = row_end[d];
    const unsigned int* hu = (const unsigned int*)hb;   // 2 bf16 per u32

    float ax = 0.f, ay = 0.f;
    #pragma unroll 1
    for (int p = 0; p < 4; ++p) {
        for (int i = beg; i < end; ++i) {
            int s = ssrc[i];
            if ((s >> 14) == p) {
                unsigned int u = hu[s * 64 + lane];
                ax += __uint_as_float(u << 16);
                ay += __uint_as_float(u & 0xFFFF0000u);
            }
        }
    }
    const float dd = dinv[d];
    unsigned int ud = hu[d * 64 + lane];
    const int f = lane * 2;
    float ox = (ax + __uint_as_float(ud << 16)) * dd + bias[f];
    float oy = (ay + __uint_as_float(ud & 0xFFFF0000u)) * dd + bias[f + 1];
    if (RELU) { ox = fmaxf(ox, 0.f); oy = fmaxf(oy, 0.f); }
    *(float2*)(ag + (size_t)d * 128 + f) = make_float2(ox, oy);
}

// CSR aggregation, 40 bf16 premultiplied features + fused log_softmax.
__global__ __launch_bounds__(256) void k_agg40_lsm(const int* __restrict__ row_start,
                                                   const int* __restrict__ row_end,
                                                   const ushort_t* __restrict__ hb,
                                                   const float* __restrict__ dinv,
                                                   const float* __restrict__ bias,
                                                   const ushort_t* __restrict__ ssrc,
                                                   float* __restrict__ out, int n) {
    const int wid = (blockIdx.x * 256 + threadIdx.x) >> 6;
    const int lane = threadIdx.x & 63;
    if (wid >= n) return;
    const int d = wid;
    const int beg = row_start[d];
    const int end = row_end[d];
    const bool act = lane < 40;
    const int f = act ? lane : 0;

    float acc = 0.f;
    int i = beg;
    for (; i + 2 <= end; i += 2) {
        int s0 = ssrc[i];
        int s1 = ssrc[i + 1];
        acc += bf2f(hb[(size_t)s0 * 40 + f]) + bf2f(hb[(size_t)s1 * 40 + f]);
    }
    if (i < end) {
        int s = ssrc[i];
        acc += bf2f(hb[(size_t)s * 40 + f]);
    }
    const float dd = dinv[d];
    float v = (acc + bf2f(hb[(size_t)d * 40 + f])) * dd + bias[f];

    float m = act ? v : -3.4e38f;
    #pragma unroll
    for (int off = 32; off; off >>= 1) m = fmaxf(m, __shfl_xor(m, off, 64));
    float ex = act ? __expf(v - m) : 0.f;
    float s = ex;
    #pragma unroll
    for (int off = 32; off; off >>= 1) s += __shfl_xor(s, off, 64);
    if (act) out[(size_t)d * 40 + lane] = v - m - logf(s);
}

extern "C" void kernel_launch(void* const* d_in, const int* in_sizes, int n_in,
                              void* d_out, int out_size, void* d_ws, size_t ws_size,
                              hipStream_t stream) {
    const float* x  = (const float*)d_in[0];
    const int*   ei = (const int*)d_in[1];
    const float* W1 = (const float*)d_in[2];
    const float* b1 = (const float*)d_in[3];
    const float* W2 = (const float*)d_in[4];
    const float* b2 = (const float*)d_in[5];
    const float* W3 = (const float*)d_in[6];
    const float* b3 = (const float*)d_in[7];
    float* out = (float*)d_out;

    const int N = in_sizes[0] / 128;
    const int E = in_sizes[1] / 2;
    const int* src = ei;
    const int* dst = ei + E;

    // workspace layout (float-sized slots)
    float* ws = (float*)d_ws;
    const int NP = 50176;                                       // N padded
    float*    dinv      = ws;                                   // NP f32
    int*      hist      = (int*)(ws + NP);                      // NP i32 (tail slot = gcounter)
    int*      row_start = (int*)(ws + 2 * NP);                  // NP i32
    int*      cursor    = (int*)(ws + 3 * NP);                  // NP i32
    ushort_t* ssrc      = (ushort_t*)(ws + 4 * NP);             // E u16
    ushort_t* hb        = (ushort_t*)(ws + 4 * NP + (E + 2) / 2 + 64); // N*128 bf16
    float*    ag        = (float*)(hb + (size_t)NP * 128);      // N*128 f32

    int* gcounter = hist + NP - 1;   // unused histogram slot (NP-1 >= N), zeroed below

    const int nblk = (N + 255) / 256;
    const int gemm_grid = (N + 31) / 32;
    const int agg_grid = (N + 3) / 4;   // 4 waves (nodes) per 256-block

    // --- build CSR (dst-sorted) + degree norm ---
    hipMemsetAsync(hist, 0, (size_t)NP * sizeof(int), stream);  // hist + gcounter
    k_hist<<<1024, 256, 0, stream>>>(dst, hist, E);
    k_alloc<<<nblk, 256, 0, stream>>>(hist, gcounter, row_start, cursor, dinv, N);
    k_scatter<<<1024, 256, 0, stream>>>(src, dst, cursor, ssrc, E);
    // cursor[i] now == row_end[i]

    // --- layer 1 ---
    k_gemm<128><<<gemm_grid, 256, 0, stream>>>(x, W1, dinv, hb, N);
    k_agg128<true><<<agg_grid, 256, 0, stream>>>(row_start, cursor, hb, dinv, b1, ssrc, ag, N);

    // --- layer 2 ---
    k_gemm<128><<<gemm_grid, 256, 0, stream>>>(ag, W2, dinv, hb, N);
    k_agg128<true><<<agg_grid, 256, 0, stream>>>(row_start, cursor, hb, dinv, b2, ssrc, ag, N);

    // --- layer 3 + log_softmax ---
    k_gemm<40><<<gemm_grid, 256, 0, stream>>>(ag, W3, dinv, hb, N);
    k_agg40_lsm<<<agg_grid, 256, 0, stream>>>(row_start, cursor, hb, dinv, b3, ssrc, out, N);
}

// Round 16
// 600.820 us; speedup vs baseline: 1.9975x; 1.9975x over previous
//
#include <hip/hip_runtime.h>
#include <cmath>

// ---------------------------------------------------------------------------
// GCN 3-layer forward on MI355X — round 16.
// vs round 15 (1200us, FAILED experiment): 4-pass src-windowing REVERTED
// (per-wave passes don't confine the per-XCD working set: waves drift ->
// combined set still 12.8MB; and 4x re-scan killed MLP: 96->365us).
// Kept: premultiplied hb = h*dinv (valid, removes dependent dinv load).
// New: (1) hb 256B-aligned (was byte 4003076 = 4 mod 256 -> every 256B row
//      straddled 5 L2 lines instead of 4, ~25% FETCH inflation + misaligned
//      uint4 stores); (2) 4-edge unrolled gather loop for MLP.
// ---------------------------------------------------------------------------

typedef unsigned short ushort_t;

__device__ __forceinline__ ushort_t f2bf(float x) {
    unsigned int u = __float_as_uint(x);
    u += 0x7FFF + ((u >> 16) & 1);   // round-to-nearest-even
    return (ushort_t)(u >> 16);
}
__device__ __forceinline__ float bf2f(ushort_t b) {
    return __uint_as_float(((unsigned int)b) << 16);
}

__global__ void k_hist(const int* __restrict__ dst, int* __restrict__ hist, int e) {
    int i = blockIdx.x * blockDim.x + threadIdx.x;
    int stride = gridDim.x * blockDim.x;
    for (; i < e; i += stride) atomicAdd(&hist[dst[i]], 1);
}

// wave-aggregated row allocation: in-wave exclusive prefix of hist via shfl,
// one atomicAdd per wave on gcounter. Row placement order is arbitrary.
__global__ void k_alloc(const int* __restrict__ hist, int* __restrict__ gcounter,
                        int* __restrict__ row_start, int* __restrict__ cursor,
                        float* __restrict__ dinv, int n) {
    const int i = blockIdx.x * blockDim.x + threadIdx.x;
    const int lane = threadIdx.x & 63;
    int h = (i < n) ? hist[i] : 0;
    int pre = h;                              // inclusive prefix within wave
    #pragma unroll
    for (int off = 1; off < 64; off <<= 1) {
        int t = __shfl_up(pre, off, 64);
        if (lane >= off) pre += t;
    }
    int wavesum = __shfl(pre, 63, 64);
    int base = 0;
    if (lane == 63) base = atomicAdd(gcounter, wavesum);
    base = __shfl(base, 63, 64);
    if (i < n) {
        int rs = base + (pre - h);            // exclusive prefix
        row_start[i] = rs;
        cursor[i] = rs;
        dinv[i] = rsqrtf(1.0f + (float)h);
    }
}

// multi-pass scatter: pass p handles dst in [p*8192,(p+1)*8192) so concurrent
// ssrc writes are confined to a ~512KB window (L2 lines fill before eviction).
__global__ void k_scatter(const int* __restrict__ src, const int* __restrict__ dst,
                          int* __restrict__ cursor, ushort_t* __restrict__ ssrc, int e) {
    const int tid0 = blockIdx.x * blockDim.x + threadIdx.x;
    const int stride = gridDim.x * blockDim.x;
    for (int p = 0; p < 7; ++p) {          // 50000>>13 == 6, so passes 0..6
        for (int i = tid0; i < e; i += stride) {
            int d = dst[i];
            if ((d >> 13) == p) {
                int pos = atomicAdd(&cursor[d], 1);
                ssrc[pos] = (ushort_t)src[i];
            }
        }
    }
}

// GEMM: hb_bf16[gr] = (in[gr] @ W) * dinv[gr]  (dinv premultiplied for agg)
template<int FOUT>
__global__ __launch_bounds__(256) void k_gemm(const float* __restrict__ in,
                                              const float* __restrict__ W,
                                              const float* __restrict__ dinv,
                                              ushort_t* __restrict__ out, int n) {
    __shared__ float Ws[128 * FOUT];
    __shared__ float Xs[32][129];
    const int tid = threadIdx.x;
    const int row0 = blockIdx.x * 32;

    for (int i = tid; i < 128 * FOUT / 4; i += 256)
        ((float4*)Ws)[i] = ((const float4*)W)[i];

    for (int i = tid; i < 1024; i += 256) {
        int r = i >> 5;
        int c = (i & 31) << 2;
        int gr = row0 + r;
        float4 v = make_float4(0.f, 0.f, 0.f, 0.f);
        if (gr < n) v = *(const float4*)(in + (size_t)gr * 128 + c);
        Xs[r][c + 0] = v.x; Xs[r][c + 1] = v.y;
        Xs[r][c + 2] = v.z; Xs[r][c + 3] = v.w;
    }
    __syncthreads();

    if constexpr (FOUT == 128) {
        const int tc = (tid & 15) * 8;
        const int tr = (tid >> 4) * 2;
        float acc0[8] = {0,0,0,0,0,0,0,0};
        float acc1[8] = {0,0,0,0,0,0,0,0};
        for (int k = 0; k < 128; ++k) {
            float a0 = Xs[tr][k];
            float a1 = Xs[tr + 1][k];
            float4 b0 = *(const float4*)&Ws[k * 128 + tc];
            float4 b1 = *(const float4*)&Ws[k * 128 + tc + 4];
            acc0[0] += a0 * b0.x; acc0[1] += a0 * b0.y;
            acc0[2] += a0 * b0.z; acc0[3] += a0 * b0.w;
            acc0[4] += a0 * b1.x; acc0[5] += a0 * b1.y;
            acc0[6] += a0 * b1.z; acc0[7] += a0 * b1.w;
            acc1[0] += a1 * b0.x; acc1[1] += a1 * b0.y;
            acc1[2] += a1 * b0.z; acc1[3] += a1 * b0.w;
            acc1[4] += a1 * b1.x; acc1[5] += a1 * b1.y;
            acc1[6] += a1 * b1.z; acc1[7] += a1 * b1.w;
        }
        int gr = row0 + tr;
        if (gr < n) {
            float dv = dinv[gr];
            uint4 o;
            o.x = (unsigned)f2bf(acc0[0]*dv) | ((unsigned)f2bf(acc0[1]*dv) << 16);
            o.y = (unsigned)f2bf(acc0[2]*dv) | ((unsigned)f2bf(acc0[3]*dv) << 16);
            o.z = (unsigned)f2bf(acc0[4]*dv) | ((unsigned)f2bf(acc0[5]*dv) << 16);
            o.w = (unsigned)f2bf(acc0[6]*dv) | ((unsigned)f2bf(acc0[7]*dv) << 16);
            *(uint4*)(out + (size_t)gr * 128 + tc) = o;
        }
        if (gr + 1 < n) {
            float dv = dinv[gr + 1];
            uint4 o;
            o.x = (unsigned)f2bf(acc1[0]*dv) | ((unsigned)f2bf(acc1[1]*dv) << 16);
            o.y = (unsigned)f2bf(acc1[2]*dv) | ((unsigned)f2bf(acc1[3]*dv) << 16);
            o.z = (unsigned)f2bf(acc1[4]*dv) | ((unsigned)f2bf(acc1[5]*dv) << 16);
            o.w = (unsigned)f2bf(acc1[6]*dv) | ((unsigned)f2bf(acc1[7]*dv) << 16);
            *(uint4*)(out + (size_t)(gr + 1) * 128 + tc) = o;
        }
    } else {
        const int tc = (tid & 7) * 5;
        const int tr = tid >> 3;
        float acc[5] = {0,0,0,0,0};
        for (int k = 0; k < 128; ++k) {
            float a = Xs[tr][k];
            #pragma unroll
            for (int j = 0; j < 5; ++j) acc[j] += a * Ws[k * 40 + tc + j];
        }
        int gr = row0 + tr;
        if (gr < n) {
            float dv = dinv[gr];
            #pragma unroll
            for (int j = 0; j < 5; ++j) out[(size_t)gr * 40 + tc + j] = f2bf(acc[j] * dv);
        }
    }
}

// CSR aggregation, 128 bf16 premultiplied features. One wave per dst node,
// lane owns 2 features (one u32). 4-edge unrolled gather for MLP.
// ag[d] = (sum_s hb[s] + hb[d]) * dinv[d] + b   (+ReLU)
template<bool RELU>
__global__ __launch_bounds__(256) void k_agg128(const int* __restrict__ row_start,
                                                const int* __restrict__ row_end,
                                                const ushort_t* __restrict__ hb,
                                                const float* __restrict__ dinv,
                                                const float* __restrict__ bias,
                                                const ushort_t* __restrict__ ssrc,
                                                float* __restrict__ ag, int n) {
    const int wid = (blockIdx.x * 256 + threadIdx.x) >> 6;
    const int lane = threadIdx.x & 63;
    if (wid >= n) return;
    const int d = wid;
    const int beg = row_start[d];
    const int end = row_end[d];
    const unsigned int* hu = (const unsigned int*)hb;   // 2 bf16 per u32

    float ax = 0.f, ay = 0.f;
    int i = beg;
    for (; i + 4 <= end; i += 4) {
        int s0 = ssrc[i];
        int s1 = ssrc[i + 1];
        int s2 = ssrc[i + 2];
        int s3 = ssrc[i + 3];
        unsigned int u0 = hu[s0 * 64 + lane];
        unsigned int u1 = hu[s1 * 64 + lane];
        unsigned int u2 = hu[s2 * 64 + lane];
        unsigned int u3 = hu[s3 * 64 + lane];
        ax += __uint_as_float(u0 << 16) + __uint_as_float(u1 << 16)
            + __uint_as_float(u2 << 16) + __uint_as_float(u3 << 16);
        ay += __uint_as_float(u0 & 0xFFFF0000u) + __uint_as_float(u1 & 0xFFFF0000u)
            + __uint_as_float(u2 & 0xFFFF0000u) + __uint_as_float(u3 & 0xFFFF0000u);
    }
    for (; i < end; ++i) {
        int s = ssrc[i];
        unsigned int u = hu[s * 64 + lane];
        ax += __uint_as_float(u << 16);
        ay += __uint_as_float(u & 0xFFFF0000u);
    }
    const float dd = dinv[d];
    unsigned int ud = hu[d * 64 + lane];
    const int f = lane * 2;
    float ox = (ax + __uint_as_float(ud << 16)) * dd + bias[f];
    float oy = (ay + __uint_as_float(ud & 0xFFFF0000u)) * dd + bias[f + 1];
    if (RELU) { ox = fmaxf(ox, 0.f); oy = fmaxf(oy, 0.f); }
    *(float2*)(ag + (size_t)d * 128 + f) = make_float2(ox, oy);
}

// CSR aggregation, 40 bf16 premultiplied features + fused log_softmax.
__global__ __launch_bounds__(256) void k_agg40_lsm(const int* __restrict__ row_start,
                                                   const int* __restrict__ row_end,
                                                   const ushort_t* __restrict__ hb,
                                                   const float* __restrict__ dinv,
                                                   const float* __restrict__ bias,
                                                   const ushort_t* __restrict__ ssrc,
                                                   float* __restrict__ out, int n) {
    const int wid = (blockIdx.x * 256 + threadIdx.x) >> 6;
    const int lane = threadIdx.x & 63;
    if (wid >= n) return;
    const int d = wid;
    const int beg = row_start[d];
    const int end = row_end[d];
    const bool act = lane < 40;
    const int f = act ? lane : 0;

    float acc = 0.f;
    int i = beg;
    for (; i + 2 <= end; i += 2) {
        int s0 = ssrc[i];
        int s1 = ssrc[i + 1];
        acc += bf2f(hb[(size_t)s0 * 40 + f]) + bf2f(hb[(size_t)s1 * 40 + f]);
    }
    if (i < end) {
        int s = ssrc[i];
        acc += bf2f(hb[(size_t)s * 40 + f]);
    }
    const float dd = dinv[d];
    float v = (acc + bf2f(hb[(size_t)d * 40 + f])) * dd + bias[f];

    float m = act ? v : -3.4e38f;
    #pragma unroll
    for (int off = 32; off; off >>= 1) m = fmaxf(m, __shfl_xor(m, off, 64));
    float ex = act ? __expf(v - m) : 0.f;
    float s = ex;
    #pragma unroll
    for (int off = 32; off; off >>= 1) s += __shfl_xor(s, off, 64);
    if (act) out[(size_t)d * 40 + lane] = v - m - logf(s);
}

extern "C" void kernel_launch(void* const* d_in, const int* in_sizes, int n_in,
                              void* d_out, int out_size, void* d_ws, size_t ws_size,
                              hipStream_t stream) {
    const float* x  = (const float*)d_in[0];
    const int*   ei = (const int*)d_in[1];
    const float* W1 = (const float*)d_in[2];
    const float* b1 = (const float*)d_in[3];
    const float* W2 = (const float*)d_in[4];
    const float* b2 = (const float*)d_in[5];
    const float* W3 = (const float*)d_in[6];
    const float* b3 = (const float*)d_in[7];
    float* out = (float*)d_out;

    const int N = in_sizes[0] / 128;
    const int E = in_sizes[1] / 2;
    const int* src = ei;
    const int* dst = ei + E;

    // workspace layout (float-sized slots; every region 256B-aligned)
    float* ws = (float*)d_ws;
    const int NP = 50176;                                 // N padded (multiple of 64)
    const size_t ssrcFloats = (((size_t)E + 1) / 2 + 63) & ~(size_t)63;  // u16 area, 256B-rounded
    float*    dinv      = ws;                             // NP f32
    int*      hist      = (int*)(ws + NP);                // NP i32 (tail slot = gcounter)
    int*      row_start = (int*)(ws + 2 * NP);            // NP i32
    int*      cursor    = (int*)(ws + 3 * NP);            // NP i32
    ushort_t* ssrc      = (ushort_t*)(ws + 4 * NP);       // E u16
    ushort_t* hb        = (ushort_t*)(ws + 4 * NP + ssrcFloats); // N*128 bf16, 256B-aligned
    float*    ag        = (float*)(hb + (size_t)NP * 128);       // N*128 f32

    int* gcounter = hist + NP - 1;   // unused histogram slot (NP-1 >= N), zeroed below

    const int nblk = (N + 255) / 256;
    const int gemm_grid = (N + 31) / 32;
    const int agg_grid = (N + 3) / 4;   // 4 waves (nodes) per 256-block

    // --- build CSR (dst-sorted) + degree norm ---
    hipMemsetAsync(hist, 0, (size_t)NP * sizeof(int), stream);  // hist + gcounter
    k_hist<<<1024, 256, 0, stream>>>(dst, hist, E);
    k_alloc<<<nblk, 256, 0, stream>>>(hist, gcounter, row_start, cursor, dinv, N);
    k_scatter<<<1024, 256, 0, stream>>>(src, dst, cursor, ssrc, E);
    // cursor[i] now == row_end[i]

    // --- layer 1 ---
    k_gemm<128><<<gemm_grid, 256, 0, stream>>>(x, W1, dinv, hb, N);
    k_agg128<true><<<agg_grid, 256, 0, stream>>>(row_start, cursor, hb, dinv, b1, ssrc, ag, N);

    // --- layer 2 ---
    k_gemm<128><<<gemm_grid, 256, 0, stream>>>(ag, W2, dinv, hb, N);
    k_agg128<true><<<agg_grid, 256, 0, stream>>>(row_start, cursor, hb, dinv, b2, ssrc, ag, N);

    // --- layer 3 + log_softmax ---
    k_gemm<40><<<gemm_grid, 256, 0, stream>>>(ag, W3, dinv, hb, N);
    k_agg40_lsm<<<agg_grid, 256, 0, stream>>>(row_start, cursor, hb, dinv, b3, ssrc, out, N);
}